// Round 1
// baseline (241.760 us; speedup 1.0000x reference)
//
#include <hip/hip_runtime.h>
#include <cstdint>

#define N_ROWS 32768
#define KDIM 1024
#define DDIM 256

typedef __attribute__((ext_vector_type(8))) short bf16x8;
typedef __attribute__((ext_vector_type(4))) float f32x4;

__device__ __forceinline__ unsigned short f2bf(float f) {
  unsigned int u = __float_as_uint(f);
  u += 0x7FFFu + ((u >> 16) & 1u);
  return (unsigned short)(u >> 16);
}
__device__ __forceinline__ float bflo(unsigned int u) { return __uint_as_float(u << 16); }
__device__ __forceinline__ float bfhi(unsigned int u) { return __uint_as_float(u & 0xFFFF0000u); }

// async global->LDS, 16B per lane. LDS dest is wave-uniform base + lane*16.
__device__ __forceinline__ void gload_lds16(const void* g, void* l) {
  __builtin_amdgcn_global_load_lds(
      (const __attribute__((address_space(1))) unsigned int*)(uintptr_t)g,
      (__attribute__((address_space(3))) unsigned int*)(unsigned int)(uintptr_t)l,
      16, 0, 0);
}

// ---------------- Kernel A: normalize codebook rows -> Cn [K,D], CnT [D,K] (bf16)
__global__ __launch_bounds__(256) void k_norm_codebook(const float* __restrict__ cb,
                                                       unsigned short* __restrict__ Cn,
                                                       unsigned short* __restrict__ CnT) {
  const int wid = threadIdx.x >> 6, lane = threadIdx.x & 63;
  const int k = blockIdx.x * 4 + wid;  // 256 blocks * 4 waves = 1024 rows
  float4 v = ((const float4*)(cb + (size_t)k * DDIM))[lane];
  float s = v.x * v.x + v.y * v.y + v.z * v.z + v.w * v.w;
#pragma unroll
  for (int m = 32; m; m >>= 1) s += __shfl_xor(s, m, 64);
  const float rn = 1.0f / sqrtf(s);
  const unsigned short b0 = f2bf(v.x * rn), b1 = f2bf(v.y * rn);
  const unsigned short b2 = f2bf(v.z * rn), b3 = f2bf(v.w * rn);
  ushort4 p; p.x = b0; p.y = b1; p.z = b2; p.w = b3;
  *(ushort4*)(Cn + (size_t)k * DDIM + lane * 4) = p;
  const int d = lane * 4;
  CnT[(size_t)(d + 0) * KDIM + k] = b0;
  CnT[(size_t)(d + 1) * KDIM + k] = b1;
  CnT[(size_t)(d + 2) * KDIM + k] = b2;
  CnT[(size_t)(d + 3) * KDIM + k] = b3;
}

// ---------------- Kernel B: normalize input rows -> Xn [N,D] bf16
__global__ __launch_bounds__(256) void k_norm_x(const float* __restrict__ x,
                                                unsigned short* __restrict__ Xn) {
  const int wid = threadIdx.x >> 6, lane = threadIdx.x & 63;
  const size_t row = (size_t)blockIdx.x * 4 + wid;  // 8192 blocks
  float4 v = ((const float4*)(x + row * DDIM))[lane];
  float s = v.x * v.x + v.y * v.y + v.z * v.z + v.w * v.w;
#pragma unroll
  for (int m = 32; m; m >>= 1) s += __shfl_xor(s, m, 64);
  const float rn = 1.0f / sqrtf(s);
  ushort4 p;
  p.x = f2bf(v.x * rn); p.y = f2bf(v.y * rn);
  p.z = f2bf(v.z * rn); p.w = f2bf(v.w * rn);
  *(ushort4*)(Xn + row * DDIM + lane * 4) = p;
}

// ---------------- Kernel C: P = exp(Xn @ Cn^T) bf16 [N,K]; r[i] = rowsum(P_i) (atomics)
__global__ __launch_bounds__(256) void k_logits(const unsigned short* __restrict__ Xn,
                                                const unsigned short* __restrict__ Cn,
                                                unsigned short* __restrict__ P,
                                                float* __restrict__ r) {
  __shared__ unsigned short At[128 * 32];
  __shared__ unsigned short Bt[128 * 32];
  __shared__ float rs[128];
  const int tid = threadIdx.x, wid = tid >> 6, lane = tid & 63;
  const int rowbase = blockIdx.y * 128, colbase = blockIdx.x * 128;
  if (tid < 128) rs[tid] = 0.f;
  const int wm = wid >> 1, wn = wid & 1;
  f32x4 acc[4][4] = {};
  const int ro_s = lane >> 2;            // row within each 16-row staging chunk
  const int cb_s = (lane & 3) * 16;      // byte offset within 64-B tile row
  for (int kb = 0; kb < DDIM; kb += 32) {
    __syncthreads();
#pragma unroll
    for (int c = 0; c < 2; ++c) {
      const int chunk = wid * 2 + c;
      const char* gA = (const char*)Xn + (size_t)(rowbase + chunk * 16 + ro_s) * (DDIM * 2) + kb * 2 + cb_s;
      gload_lds16(gA, (char*)At + chunk * 1024);
      const char* gB = (const char*)Cn + (size_t)(colbase + chunk * 16 + ro_s) * (DDIM * 2) + kb * 2 + cb_s;
      gload_lds16(gB, (char*)Bt + chunk * 1024);
    }
    __syncthreads();
    bf16x8 a[4], b[4];
#pragma unroll
    for (int mi = 0; mi < 4; ++mi)
      a[mi] = *(const bf16x8*)&At[(wm * 64 + mi * 16 + (lane & 15)) * 32 + (lane >> 4) * 8];
#pragma unroll
    for (int ni = 0; ni < 4; ++ni)
      b[ni] = *(const bf16x8*)&Bt[(wn * 64 + ni * 16 + (lane & 15)) * 32 + (lane >> 4) * 8];
#pragma unroll
    for (int mi = 0; mi < 4; ++mi)
#pragma unroll
      for (int ni = 0; ni < 4; ++ni)
        acc[mi][ni] = __builtin_amdgcn_mfma_f32_16x16x32_bf16(a[mi], b[ni], acc[mi][ni], 0, 0, 0);
  }
  // epilogue: P = exp(logit) (logit in [-1,1], no max needed), rowsum accumulation
#pragma unroll
  for (int mi = 0; mi < 4; ++mi) {
    const int rloc = wm * 64 + mi * 16 + (lane >> 4) * 4;
    float vsum[4] = {0.f, 0.f, 0.f, 0.f};
#pragma unroll
    for (int ni = 0; ni < 4; ++ni) {
      const int col = colbase + wn * 64 + ni * 16 + (lane & 15);
#pragma unroll
      for (int reg = 0; reg < 4; ++reg) {
        const float e = __expf(acc[mi][ni][reg]);
        vsum[reg] += e;
        P[(size_t)(rowbase + rloc + reg) * KDIM + col] = f2bf(e);
      }
    }
#pragma unroll
    for (int reg = 0; reg < 4; ++reg) atomicAdd(&rs[rloc + reg], vsum[reg]);
  }
  __syncthreads();
  if (tid < 128) atomicAdd(&r[rowbase + tid], rs[tid]);
}

// ---------------- Kernel D: recon = (P @ CnT^T) * (1/r) -> fp32 [N,D]
__global__ __launch_bounds__(256) void k_recon(const unsigned short* __restrict__ P,
                                               const unsigned short* __restrict__ CnT,
                                               const float* __restrict__ r,
                                               float* __restrict__ out) {
  __shared__ unsigned short At[128 * 32];
  __shared__ unsigned short Bt[128 * 32];
  __shared__ float invr[128];
  const int tid = threadIdx.x, wid = tid >> 6, lane = tid & 63;
  const int rowbase = blockIdx.y * 128, colbase = blockIdx.x * 128;
  if (tid < 128) invr[tid] = 1.0f / r[rowbase + tid];
  const int wm = wid >> 1, wn = wid & 1;
  f32x4 acc[4][4] = {};
  const int ro_s = lane >> 2;
  const int cb_s = (lane & 3) * 16;
  for (int kb = 0; kb < KDIM; kb += 32) {
    __syncthreads();
#pragma unroll
    for (int c = 0; c < 2; ++c) {
      const int chunk = wid * 2 + c;
      const char* gA = (const char*)P + (size_t)(rowbase + chunk * 16 + ro_s) * (KDIM * 2) + kb * 2 + cb_s;
      gload_lds16(gA, (char*)At + chunk * 1024);
      const char* gB = (const char*)CnT + (size_t)(colbase + chunk * 16 + ro_s) * (KDIM * 2) + kb * 2 + cb_s;
      gload_lds16(gB, (char*)Bt + chunk * 1024);
    }
    __syncthreads();
    bf16x8 a[4], b[4];
#pragma unroll
    for (int mi = 0; mi < 4; ++mi)
      a[mi] = *(const bf16x8*)&At[(wm * 64 + mi * 16 + (lane & 15)) * 32 + (lane >> 4) * 8];
#pragma unroll
    for (int ni = 0; ni < 4; ++ni)
      b[ni] = *(const bf16x8*)&Bt[(wn * 64 + ni * 16 + (lane & 15)) * 32 + (lane >> 4) * 8];
#pragma unroll
    for (int mi = 0; mi < 4; ++mi)
#pragma unroll
      for (int ni = 0; ni < 4; ++ni)
        acc[mi][ni] = __builtin_amdgcn_mfma_f32_16x16x32_bf16(a[mi], b[ni], acc[mi][ni], 0, 0, 0);
  }
#pragma unroll
  for (int mi = 0; mi < 4; ++mi) {
    const int rloc = wm * 64 + mi * 16 + (lane >> 4) * 4;
#pragma unroll
    for (int ni = 0; ni < 4; ++ni) {
      const int col = colbase + wn * 64 + ni * 16 + (lane & 15);
#pragma unroll
      for (int reg = 0; reg < 4; ++reg) {
        const int row = rowbase + rloc + reg;
        out[(size_t)row * DDIM + col] = acc[mi][ni][reg] * invr[rloc + reg];
      }
    }
  }
}

// ---------------- Kernel E: colsum[k] = sum_i P_ik/r_i ; sLSE += log(sum_k exp(P_ik/r_i))
__global__ __launch_bounds__(256) void k_stats(const unsigned short* __restrict__ P,
                                               const float* __restrict__ r,
                                               float* __restrict__ colsum,
                                               float* __restrict__ sLSE) {
  __shared__ float csl[1024];
  const int tid = threadIdx.x, wid = tid >> 6, lane = tid & 63;
  for (int j = tid; j < 1024; j += 256) csl[j] = 0.f;
  __syncthreads();
  float cs[16];
#pragma unroll
  for (int c = 0; c < 16; ++c) cs[c] = 0.f;
  float lse_acc = 0.f;
  const int row0 = blockIdx.x * 128 + wid * 32;  // 256 blocks, 4 waves, 32 rows/wave
  for (int j = 0; j < 32; ++j) {
    const int row = row0 + j;
    const float inv = 1.0f / r[row];
    const uint4* pr = (const uint4*)(P + (size_t)row * KDIM + lane * 16);
    const uint4 q0 = pr[0], q1 = pr[1];
    float f[16];
    f[0] = bflo(q0.x);  f[1] = bfhi(q0.x);  f[2] = bflo(q0.y);  f[3] = bfhi(q0.y);
    f[4] = bflo(q0.z);  f[5] = bfhi(q0.z);  f[6] = bflo(q0.w);  f[7] = bfhi(q0.w);
    f[8] = bflo(q1.x);  f[9] = bfhi(q1.x);  f[10] = bflo(q1.y); f[11] = bfhi(q1.y);
    f[12] = bflo(q1.z); f[13] = bfhi(q1.z); f[14] = bflo(q1.w); f[15] = bfhi(q1.w);
    float es = 0.f;
#pragma unroll
    for (int c = 0; c < 16; ++c) {
      const float d = f[c] * inv;
      cs[c] += d;
      es += __expf(d);
    }
#pragma unroll
    for (int m = 32; m; m >>= 1) es += __shfl_xor(es, m, 64);
    if (lane == 0) lse_acc += logf(es);
  }
#pragma unroll
  for (int c = 0; c < 16; ++c) atomicAdd(&csl[lane * 16 + c], cs[c]);
  if (lane == 0) atomicAdd(sLSE, lse_acc);
  __syncthreads();
  for (int j = tid; j < 1024; j += 256) atomicAdd(&colsum[j], csl[j]);
}

// ---------------- Kernel F: finalize loss
__global__ __launch_bounds__(256) void k_final(const float* __restrict__ colsum,
                                               const float* __restrict__ sLSE,
                                               float* __restrict__ out) {
  __shared__ float r1[256], r2[256];
  const int tid = threadIdx.x;
  float s1 = 0.f, s2 = 0.f;
  for (int j = tid; j < KDIM; j += 256) {
    const float v = colsum[j];
    s1 += v;
    s2 += v * v;
  }
  r1[tid] = s1; r2[tid] = s2;
  __syncthreads();
  for (int o = 128; o; o >>= 1) {
    if (tid < o) { r1[tid] += r1[tid + o]; r2[tid] += r2[tid + o]; }
    __syncthreads();
  }
  if (tid == 0) {
    const double S = r1[0];          // sum of all distances (~N)
    const double Q = r2[0];          // ||colsum||^2
    const double L = sLSE[0];        // sum_i LSE_i
    const double entropy = (S * L - Q) / (double)N_ROWS;
    const double l1 = S / ((double)N_ROWS * (double)KDIM);
    out[(size_t)N_ROWS * DDIM] = (float)(1000.0 * l1 + 5e-5 * entropy);
  }
}

extern "C" void kernel_launch(void* const* d_in, const int* in_sizes, int n_in,
                              void* d_out, int out_size, void* d_ws, size_t ws_size,
                              hipStream_t stream) {
  const float* x = (const float*)d_in[0];   // [8,4096,256] fp32
  const float* cb = (const float*)d_in[1];  // [1024,256] fp32
  float* out = (float*)d_out;               // recon [8388608] + loss [1]
  char* ws = (char*)d_ws;

  // workspace layout (256-B aligned offsets)
  float* r            = (float*)(ws + 0);          // 131072 B
  float* colsum       = (float*)(ws + 131072);     // 4096 B
  float* sLSE         = (float*)(ws + 135168);     // 256 B
  unsigned short* Cn  = (unsigned short*)(ws + 135424);    // 524288 B
  unsigned short* CnT = (unsigned short*)(ws + 659712);    // 524288 B
  unsigned short* Xn  = (unsigned short*)(ws + 1184000);   // 16777216 B
  unsigned short* P   = (unsigned short*)(ws + 17961216);  // 67108864 B

  hipMemsetAsync(ws, 0, 135424, stream);  // zero r, colsum, sLSE (ws is poisoned each call)
  k_norm_codebook<<<256, 256, 0, stream>>>(cb, Cn, CnT);
  k_norm_x<<<8192, 256, 0, stream>>>(x, Xn);
  k_logits<<<dim3(8, 256), 256, 0, stream>>>(Xn, Cn, P, r);
  k_recon<<<dim3(2, 256), 256, 0, stream>>>(P, CnT, r, out);
  k_stats<<<256, 256, 0, stream>>>(P, r, colsum, sLSE);
  k_final<<<1, 256, 0, stream>>>(colsum, sLSE, out);
}

// Round 2
// 193.783 us; speedup vs baseline: 1.2476x; 1.2476x over previous
//
#include <hip/hip_runtime.h>
#include <cstdint>

#define N_ROWS 32768
#define KDIM 1024
#define DDIM 256

typedef __attribute__((ext_vector_type(8))) short bf16x8;
typedef __attribute__((ext_vector_type(4))) float f32x4;

__device__ __forceinline__ unsigned short f2bf(float f) {
  unsigned int u = __float_as_uint(f);
  u += 0x7FFFu + ((u >> 16) & 1u);
  return (unsigned short)(u >> 16);
}

// async global->LDS, 16B per lane. LDS dest is wave-uniform base + lane*16.
__device__ __forceinline__ void gload_lds16(const void* g, void* l) {
  __builtin_amdgcn_global_load_lds(
      (const __attribute__((address_space(1))) unsigned int*)(uintptr_t)g,
      (__attribute__((address_space(3))) unsigned int*)(unsigned int)(uintptr_t)l,
      16, 0, 0);
}

// ---------------- Kernel A: normalize codebook rows -> Cn [K,D], CnT [D,K] (bf16)
__global__ __launch_bounds__(256) void k_norm_codebook(const float* __restrict__ cb,
                                                       unsigned short* __restrict__ Cn,
                                                       unsigned short* __restrict__ CnT) {
  const int wid = threadIdx.x >> 6, lane = threadIdx.x & 63;
  const int k = blockIdx.x * 4 + wid;  // 256 blocks * 4 waves = 1024 rows
  float4 v = ((const float4*)(cb + (size_t)k * DDIM))[lane];
  float s = v.x * v.x + v.y * v.y + v.z * v.z + v.w * v.w;
#pragma unroll
  for (int m = 32; m; m >>= 1) s += __shfl_xor(s, m, 64);
  const float rn = 1.0f / sqrtf(s);
  const unsigned short b0 = f2bf(v.x * rn), b1 = f2bf(v.y * rn);
  const unsigned short b2 = f2bf(v.z * rn), b3 = f2bf(v.w * rn);
  ushort4 p; p.x = b0; p.y = b1; p.z = b2; p.w = b3;
  *(ushort4*)(Cn + (size_t)k * DDIM + lane * 4) = p;
  const int d = lane * 4;
  CnT[(size_t)(d + 0) * KDIM + k] = b0;
  CnT[(size_t)(d + 1) * KDIM + k] = b1;
  CnT[(size_t)(d + 2) * KDIM + k] = b2;
  CnT[(size_t)(d + 3) * KDIM + k] = b3;
}

// ---------------- Fused kernel: per block of 64 rows, do everything.
// Pass 1 per K-tile (128 codes): S = Xn@Cn^T (MFMA), e=exp(S)->Ps(LDS),
//   r += rowsum(e), q += rowsum(e^2), O += Ps@Cn (MFMA via CnT).
// Then LSE_i = log(K+1+q/(2r^2)) (series; d~1e-3 so error ~1e-9).
// Pass 2 per K-tile: recompute S, colsum_k += sum_i exp(s)/r_i.
// Epilogue: out = O * (1/r).
__global__ __launch_bounds__(256, 2) void k_fused(const float* __restrict__ x,
                                                  const unsigned short* __restrict__ Cn,
                                                  const unsigned short* __restrict__ CnT,
                                                  float* __restrict__ colsum,
                                                  float* __restrict__ sLSE,
                                                  float* __restrict__ out) {
  __shared__ unsigned short Xs[64 * 264];   // 64 rows x 256 (+8 pad) bf16 = 33792 B
  __shared__ unsigned short Ps[64 * 136];   // 64 rows x 128 (+8 pad) bf16 = 17408 B
  __shared__ unsigned short Cbuf[8192];     // union: Ct 128x32 (S-phase) / CtT 256x32 (PV)
  __shared__ float csl[1024];
  __shared__ float r_l[64], q_l[64], ir_l[64];

  const int tid = threadIdx.x, wid = tid >> 6, lane = tid & 63;
  const int l15 = lane & 15, l4 = lane >> 4;
  const int wm = wid >> 1, wn = wid & 1;
  const int rowbase = blockIdx.x * 64;

  if (tid < 64) { r_l[tid] = 0.f; q_l[tid] = 0.f; }
  for (int j = tid; j < 1024; j += 256) csl[j] = 0.f;

  // Phase 0: load + row-normalize X -> Xs (bf16). 16 rows per wave.
  for (int rr = 0; rr < 16; ++rr) {
    const int row = wid * 16 + rr;
    float4 v = ((const float4*)(x + (size_t)(rowbase + row) * DDIM))[lane];
    float s = v.x * v.x + v.y * v.y + v.z * v.z + v.w * v.w;
#pragma unroll
    for (int m = 32; m; m >>= 1) s += __shfl_xor(s, m, 64);
    const float rn = 1.0f / sqrtf(s);
    ushort4 p;
    p.x = f2bf(v.x * rn); p.y = f2bf(v.y * rn);
    p.z = f2bf(v.z * rn); p.w = f2bf(v.w * rn);
    *(ushort4*)&Xs[row * 264 + lane * 4] = p;
  }

  f32x4 O[2][8] = {};  // persistent PV accumulator: rows wm*32+mi*16, cols wn*128+ni*16

  // ---------------- Pass 1 ----------------
  for (int kt = 0; kt < 8; ++kt) {
    const int kc = kt * 128;
    f32x4 S[2][4] = {};
    for (int kb = 0; kb < 8; ++kb) {
      __syncthreads();
#pragma unroll
      for (int c = 0; c < 2; ++c) {
        const int chunk = wid * 2 + c;
        const char* g = (const char*)(Cn + (size_t)(kc + chunk * 16 + (lane >> 2)) * DDIM + kb * 32 + (lane & 3) * 8);
        gload_lds16(g, (char*)Cbuf + chunk * 1024);
      }
      __syncthreads();
      bf16x8 a[2], b[4];
#pragma unroll
      for (int mi = 0; mi < 2; ++mi)
        a[mi] = *(const bf16x8*)&Xs[(wm * 32 + mi * 16 + l15) * 264 + kb * 32 + l4 * 8];
#pragma unroll
      for (int ni = 0; ni < 4; ++ni)
        b[ni] = *(const bf16x8*)&Cbuf[(wn * 64 + ni * 16 + l15) * 32 + l4 * 8];
#pragma unroll
      for (int mi = 0; mi < 2; ++mi)
#pragma unroll
        for (int ni = 0; ni < 4; ++ni)
          S[mi][ni] = __builtin_amdgcn_mfma_f32_16x16x32_bf16(a[mi], b[ni], S[mi][ni], 0, 0, 0);
    }
    // epilogue: e = exp(s) -> Ps; r,q accumulation (shuffle-reduce + 2-way LDS atomics)
#pragma unroll
    for (int mi = 0; mi < 2; ++mi) {
#pragma unroll
      for (int reg = 0; reg < 4; ++reg) {
        const int row = wm * 32 + mi * 16 + l4 * 4 + reg;
        float se = 0.f, sq = 0.f;
#pragma unroll
        for (int ni = 0; ni < 4; ++ni) {
          const float e = __expf(S[mi][ni][reg]);
          se += e; sq += e * e;
          Ps[row * 136 + wn * 64 + ni * 16 + l15] = f2bf(e);
        }
#pragma unroll
        for (int m = 1; m < 16; m <<= 1) { se += __shfl_xor(se, m, 64); sq += __shfl_xor(sq, m, 64); }
        if (l15 == 0) { atomicAdd(&r_l[row], se); atomicAdd(&q_l[row], sq); }
      }
    }
    // PV: O += Ps @ Cn_kt  (B^T from CnT)
    for (int k2 = 0; k2 < 4; ++k2) {
      __syncthreads();
#pragma unroll
      for (int c = 0; c < 4; ++c) {
        const int chunk = wid * 4 + c;
        const char* g = (const char*)(CnT + (size_t)(chunk * 16 + (lane >> 2)) * KDIM + kc + k2 * 32 + (lane & 3) * 8);
        gload_lds16(g, (char*)Cbuf + chunk * 1024);
      }
      __syncthreads();
      bf16x8 a[2], b[8];
#pragma unroll
      for (int mi = 0; mi < 2; ++mi)
        a[mi] = *(const bf16x8*)&Ps[(wm * 32 + mi * 16 + l15) * 136 + k2 * 32 + l4 * 8];
#pragma unroll
      for (int ni = 0; ni < 8; ++ni)
        b[ni] = *(const bf16x8*)&Cbuf[(wn * 128 + ni * 16 + l15) * 32 + l4 * 8];
#pragma unroll
      for (int mi = 0; mi < 2; ++mi)
#pragma unroll
        for (int ni = 0; ni < 8; ++ni)
          O[mi][ni] = __builtin_amdgcn_mfma_f32_16x16x32_bf16(a[mi], b[ni], O[mi][ni], 0, 0, 0);
    }
  }

  // finalize r; LSE via series: sum_k exp(d) = K + 1 + q/(2 r^2)
  __syncthreads();
  if (tid < 64) {
    const float r = r_l[tid];
    const float ir = 1.0f / r;
    ir_l[tid] = ir;
    float lse = logf((float)(KDIM + 1) + 0.5f * q_l[tid] * ir * ir);
#pragma unroll
    for (int m = 32; m; m >>= 1) lse += __shfl_xor(lse, m, 64);
    if (tid == 0) atomicAdd(sLSE, lse);
  }
  __syncthreads();

  float irv[2][4];
#pragma unroll
  for (int mi = 0; mi < 2; ++mi)
#pragma unroll
    for (int reg = 0; reg < 4; ++reg)
      irv[mi][reg] = ir_l[wm * 32 + mi * 16 + l4 * 4 + reg];

  // ---------------- Pass 2: recompute S, accumulate colsum ----------------
  for (int kt = 0; kt < 8; ++kt) {
    const int kc = kt * 128;
    f32x4 S[2][4] = {};
    for (int kb = 0; kb < 8; ++kb) {
      __syncthreads();
#pragma unroll
      for (int c = 0; c < 2; ++c) {
        const int chunk = wid * 2 + c;
        const char* g = (const char*)(Cn + (size_t)(kc + chunk * 16 + (lane >> 2)) * DDIM + kb * 32 + (lane & 3) * 8);
        gload_lds16(g, (char*)Cbuf + chunk * 1024);
      }
      __syncthreads();
      bf16x8 a[2], b[4];
#pragma unroll
      for (int mi = 0; mi < 2; ++mi)
        a[mi] = *(const bf16x8*)&Xs[(wm * 32 + mi * 16 + l15) * 264 + kb * 32 + l4 * 8];
#pragma unroll
      for (int ni = 0; ni < 4; ++ni)
        b[ni] = *(const bf16x8*)&Cbuf[(wn * 64 + ni * 16 + l15) * 32 + l4 * 8];
#pragma unroll
      for (int mi = 0; mi < 2; ++mi)
#pragma unroll
        for (int ni = 0; ni < 4; ++ni)
          S[mi][ni] = __builtin_amdgcn_mfma_f32_16x16x32_bf16(a[mi], b[ni], S[mi][ni], 0, 0, 0);
    }
    // colsum_k += sum_rows exp(s) / r_i
#pragma unroll
    for (int ni = 0; ni < 4; ++ni) {
      float v = 0.f;
#pragma unroll
      for (int mi = 0; mi < 2; ++mi)
#pragma unroll
        for (int reg = 0; reg < 4; ++reg)
          v += __expf(S[mi][ni][reg]) * irv[mi][reg];
      v += __shfl_xor(v, 16, 64);
      v += __shfl_xor(v, 32, 64);
      if (l4 == 0) atomicAdd(&csl[kc + wn * 64 + ni * 16 + l15], v);
    }
  }

  __syncthreads();
  for (int j = tid; j < 1024; j += 256) atomicAdd(&colsum[j], csl[j]);

  // O epilogue: scale by 1/r, store fp32
#pragma unroll
  for (int mi = 0; mi < 2; ++mi)
#pragma unroll
    for (int ni = 0; ni < 8; ++ni)
#pragma unroll
      for (int reg = 0; reg < 4; ++reg) {
        const int row = wm * 32 + mi * 16 + l4 * 4 + reg;
        const int col = wn * 128 + ni * 16 + l15;
        out[(size_t)(rowbase + row) * DDIM + col] = O[mi][ni][reg] * irv[mi][reg];
      }
}

// ---------------- Finalize loss
__global__ __launch_bounds__(256) void k_final(const float* __restrict__ colsum,
                                               const float* __restrict__ sLSE,
                                               float* __restrict__ out) {
  __shared__ float r1[256], r2[256];
  const int tid = threadIdx.x;
  float s1 = 0.f, s2 = 0.f;
  for (int j = tid; j < KDIM; j += 256) {
    const float v = colsum[j];
    s1 += v;
    s2 += v * v;
  }
  r1[tid] = s1; r2[tid] = s2;
  __syncthreads();
  for (int o = 128; o; o >>= 1) {
    if (tid < o) { r1[tid] += r1[tid + o]; r2[tid] += r2[tid + o]; }
    __syncthreads();
  }
  if (tid == 0) {
    const double S = r1[0];          // sum of all distances (~N)
    const double Q = r2[0];          // ||colsum||^2
    const double L = sLSE[0];        // sum_i LSE_i
    const double entropy = (S * L - Q) / (double)N_ROWS;
    const double l1 = S / ((double)N_ROWS * (double)KDIM);
    out[(size_t)N_ROWS * DDIM] = (float)(1000.0 * l1 + 5e-5 * entropy);
  }
}

extern "C" void kernel_launch(void* const* d_in, const int* in_sizes, int n_in,
                              void* d_out, int out_size, void* d_ws, size_t ws_size,
                              hipStream_t stream) {
  const float* x = (const float*)d_in[0];   // [8,4096,256] fp32
  const float* cb = (const float*)d_in[1];  // [1024,256] fp32
  float* out = (float*)d_out;               // recon [8388608] + loss [1]
  char* ws = (char*)d_ws;

  // workspace layout (256-B aligned offsets)
  float* colsum       = (float*)(ws + 0);        // 4096 B
  float* sLSE         = (float*)(ws + 4096);     // 256 B
  unsigned short* Cn  = (unsigned short*)(ws + 4352);    // 524288 B
  unsigned short* CnT = (unsigned short*)(ws + 528640);  // 524288 B

  hipMemsetAsync(ws, 0, 4352, stream);  // zero colsum + sLSE
  k_norm_codebook<<<256, 256, 0, stream>>>(cb, Cn, CnT);
  k_fused<<<512, 256, 0, stream>>>(x, Cn, CnT, colsum, sLSE, out);
  k_final<<<1, 256, 0, stream>>>(colsum, sLSE, out);
}